// Round 5
// baseline (642.963 us; speedup 1.0000x reference)
//
#include <hip/hip_runtime.h>
#include <hip/hip_bf16.h>
#include <cstdint>
#include <cstddef>

typedef short bf16x8 __attribute__((ext_vector_type(8)));
typedef float f32x4 __attribute__((ext_vector_type(4)));
typedef unsigned short u16x4v __attribute__((ext_vector_type(4)));

__device__ __forceinline__ float bf2f(unsigned short u) {
  union { unsigned int u; float f; } v; v.u = ((unsigned int)u) << 16; return v.f;
}
__device__ __forceinline__ unsigned short f2bf(float f) {
  union { float f; unsigned int u; } v; v.f = f;
  unsigned int r = v.u + 0x7fffu + ((v.u >> 16) & 1u);
  return (unsigned short)(r >> 16);
}
__device__ __forceinline__ int pack2(float a, float b) {
  return (int)f2bf(a) | ((int)f2bf(b) << 16);
}
// async global->LDS, 16B per lane; LDS dest is wave-uniform base + lane*16
__device__ __forceinline__ void gll16(const void* g, void* l) {
  __builtin_amdgcn_global_load_lds(
      (const __attribute__((address_space(1))) unsigned int*)g,
      (__attribute__((address_space(3))) unsigned int*)l, 16, 0, 0);
}

// ---------------- all-weight transpose+convert in ONE kernel ----------------
struct WPack {
  const float* in[6];
  unsigned short* out[6];
  int K[6], Ncol[6];
  int start[7];
};
__global__ __launch_bounds__(256) void convert_all(WPack p) {
  int idx = blockIdx.x * 256 + threadIdx.x;
  #pragma unroll
  for (int s = 0; s < 6; ++s) {
    if (idx >= p.start[s] && idx < p.start[s + 1]) {
      int lidx = idx - p.start[s];
      int k = lidx / p.Ncol[s], n = lidx % p.Ncol[s];
      p.out[s][n * p.K[s] + k] = f2bf(p.in[s][lidx]);
    }
  }
}

// ---------------- GEMM: C[M,Ncol] = A[M,K] @ Wt[Ncol,K]^T (f32 acc, bf16 out)
// AF32: A is f32, reg-staged+converted. GLL: A,B bf16 via global_load_lds
// (requires A rows valid up to gx*128 — buffers are padded).
template<int BN, int WAVES_M, int WAVES_N, bool AF32, bool GLL>
__global__ __launch_bounds__(256) void gemm_dual(
    const void* __restrict__ Av,
    const unsigned short* __restrict__ BtL, const unsigned short* __restrict__ BtR,
    unsigned short* __restrict__ outL, unsigned short* __restrict__ outR,
    int M, int K, int Ncol) {
  constexpr int BM = 128, BK = 64;
  constexpr int WTM = BM / WAVES_M, WTN = BN / WAVES_N;
  constexpr int MR = WTM / 16, NR = WTN / 16;
  const unsigned short* __restrict__ Bt = blockIdx.z ? BtR : BtL;
  unsigned short* __restrict__ outp = blockIdx.z ? outR : outL;

  __shared__ alignas(16) unsigned short lAt[BM * BK];
  __shared__ alignas(16) unsigned short lBt[BN * BK];

  int t = threadIdx.x;
  int lane = t & 63, wid = t >> 6;
  int wm = wid / WAVES_N, wn = wid % WAVES_N;
  int rowBase = blockIdx.x * BM;
  int colBase = blockIdx.y * BN;

  f32x4 acc[MR][NR] = {};

  for (int k0 = 0; k0 < K; k0 += BK) {
    if constexpr (GLL) {
      // A: 16 chunks of 1KB (8 rows x 128B each); wave covers BM/32 chunks.
      const unsigned short* A = (const unsigned short*)Av;
      #pragma unroll
      for (int p = 0; p < BM / 32; ++p) {
        int chunk = wid * (BM / 32) + p;
        int row = chunk * 8 + (lane >> 3);
        int c = (lane & 7) ^ (row & 7);   // pre-swizzled source, linear LDS dest
        gll16(A + (size_t)(rowBase + row) * K + k0 + c * 8, &lAt[chunk * 512]);
      }
      #pragma unroll
      for (int p = 0; p < BN / 32; ++p) {
        int chunk = wid * (BN / 32) + p;
        int row = chunk * 8 + (lane >> 3);
        int c = (lane & 7) ^ (row & 7);
        gll16(Bt + (size_t)(colBase + row) * K + k0 + c * 8, &lBt[chunk * 512]);
      }
    } else {
      #pragma unroll
      for (int p = 0; p < (BM * 8) / 256; ++p) {
        int lin = p * 256 + t;
        int row = lin >> 3, c = lin & 7;
        int gr = rowBase + row;
        int4 w = make_int4(0, 0, 0, 0);
        if constexpr (AF32) {
          const float* A = (const float*)Av;
          if (gr < M) {
            const float* ap = A + (size_t)gr * K + k0 + c * 8;
            f32x4 f0 = *reinterpret_cast<const f32x4*>(ap);
            f32x4 f1 = *reinterpret_cast<const f32x4*>(ap + 4);
            w.x = pack2(f0[0], f0[1]); w.y = pack2(f0[2], f0[3]);
            w.z = pack2(f1[0], f1[1]); w.w = pack2(f1[2], f1[3]);
          }
        } else {
          const unsigned short* A = (const unsigned short*)Av;
          if (gr < M) w = *reinterpret_cast<const int4*>(A + (size_t)gr * K + k0 + c * 8);
        }
        *reinterpret_cast<int4*>(&lAt[row * 64 + ((c ^ (row & 7)) * 8)]) = w;
      }
      #pragma unroll
      for (int p = 0; p < (BN * 8) / 256; ++p) {
        int lin = p * 256 + t;
        int row = lin >> 3, c = lin & 7;
        int4 v = *reinterpret_cast<const int4*>(Bt + (size_t)(colBase + row) * K + k0 + c * 8);
        *reinterpret_cast<int4*>(&lBt[row * 64 + ((c ^ (row & 7)) * 8)]) = v;
      }
    }
    __syncthreads();
    #pragma unroll
    for (int kk = 0; kk < 2; ++kk) {
      bf16x8 af[MR], bfr[NR];
      int cidx = kk * 4 + (lane >> 4);
      #pragma unroll
      for (int mi = 0; mi < MR; ++mi) {
        int row = wm * WTM + mi * 16 + (lane & 15);
        af[mi] = *reinterpret_cast<const bf16x8*>(&lAt[row * 64 + ((cidx ^ (row & 7)) * 8)]);
      }
      #pragma unroll
      for (int ni = 0; ni < NR; ++ni) {
        int row = wn * WTN + ni * 16 + (lane & 15);
        bfr[ni] = *reinterpret_cast<const bf16x8*>(&lBt[row * 64 + ((cidx ^ (row & 7)) * 8)]);
      }
      #pragma unroll
      for (int mi = 0; mi < MR; ++mi)
        #pragma unroll
        for (int ni = 0; ni < NR; ++ni)
          acc[mi][ni] = __builtin_amdgcn_mfma_f32_16x16x32_bf16(af[mi], bfr[ni], acc[mi][ni], 0, 0, 0);
    }
    __syncthreads();
  }
  #pragma unroll
  for (int mi = 0; mi < MR; ++mi)
    #pragma unroll
    for (int ni = 0; ni < NR; ++ni) {
      int col = colBase + wn * WTN + ni * 16 + (lane & 15);
      #pragma unroll
      for (int r = 0; r < 4; ++r) {
        int row = rowBase + wm * WTM + mi * 16 + (lane >> 4) * 4 + r;
        if (row < M) outp[(size_t)row * Ncol + col] = f2bf(acc[mi][ni][r]);
      }
    }
}

// ---------------- CSR build ----------------
__global__ __launch_bounds__(256) void hist_kernel(const int* __restrict__ dst, int* __restrict__ counts, int E) {
  int e = blockIdx.x * 256 + threadIdx.x;
  if (e < E) atomicAdd(&counts[dst[e]], 1);
}

__global__ __launch_bounds__(256) void scan_block(const int* __restrict__ in, int* __restrict__ out,
                                                  int* __restrict__ sums, int n) {
  int i = blockIdx.x * 256 + threadIdx.x;
  int lane = threadIdx.x & 63, wid = threadIdx.x >> 6;
  int v = (i < n) ? in[i] : 0;
  int s = v;
  #pragma unroll
  for (int d = 1; d < 64; d <<= 1) { int tt = __shfl_up(s, d); if (lane >= d) s += tt; }
  __shared__ int wsum[4];
  if (lane == 63) wsum[wid] = s;
  __syncthreads();
  int off = 0;
  for (int w = 0; w < wid; ++w) off += wsum[w];
  if (i < n) out[i] = off + s - v;  // exclusive
  if (threadIdx.x == 255) sums[blockIdx.x] = off + s;
}

__global__ __launch_bounds__(256) void scan_add(int* __restrict__ rs, const int* __restrict__ boffs,
                                                int* __restrict__ cursor, int n, int E) {
  int i = blockIdx.x * 256 + threadIdx.x;
  if (i < n) {
    int v = rs[i] + boffs[blockIdx.x];
    rs[i] = v;
    cursor[i] = v;
  }
  if (i == 0) rs[n] = E;
}

__global__ __launch_bounds__(256) void scatter_kernel(const int* __restrict__ src, const int* __restrict__ dst,
                                                      int* __restrict__ cursor, int* __restrict__ csr, int E) {
  int e = blockIdx.x * 256 + threadIdx.x;
  if (e < E) {
    int p = atomicAdd(&cursor[dst[e]], 1);
    csr[p] = src[e];
  }
}

// ---------------- degree-descending (LPT) node permutation ----------------
__global__ __launch_bounds__(256) void deg_hist(const int* __restrict__ rs, int* __restrict__ bcount, int N) {
  __shared__ int lh[256];
  lh[threadIdx.x] = 0;
  __syncthreads();
  int n = blockIdx.x * 256 + threadIdx.x;
  if (n < N) {
    int d = rs[n + 1] - rs[n];
    if (d > 255) d = 255;
    atomicAdd(&lh[d], 1);
  }
  __syncthreads();
  if (lh[threadIdx.x]) atomicAdd(&bcount[threadIdx.x], lh[threadIdx.x]);
}

__global__ __launch_bounds__(256) void deg_offsets(const int* __restrict__ bcount, int* __restrict__ dcur) {
  // dcur[d] = sum_{d'>d} bcount[d']  (descending-degree base offsets)
  int t = threadIdx.x;
  int lane = t & 63, w = t >> 6;
  int v = bcount[255 - t];
  int s = v;
  #pragma unroll
  for (int d1 = 1; d1 < 64; d1 <<= 1) { int tt = __shfl_up(s, d1); if (lane >= d1) s += tt; }
  __shared__ int ws[4];
  if (lane == 63) ws[w] = s;
  __syncthreads();
  int off = 0;
  for (int u = 0; u < w; ++u) off += ws[u];
  dcur[255 - t] = off + s - v;  // exclusive over reversed order
}

__global__ __launch_bounds__(256) void deg_scatter(const int* __restrict__ rs, int* __restrict__ dcur,
                                                   int* __restrict__ perm, int N) {
  int n = blockIdx.x * 256 + threadIdx.x;
  if (n < N) {
    int d = rs[n + 1] - rs[n];
    if (d > 255) d = 255;
    perm[atomicAdd(&dcur[d], 1)] = n;
  }
}

// ---------------- edge aggregation helpers ----------------
template<int VEC>
__device__ __forceinline__ void load_row(const unsigned short* __restrict__ base,
                                         int s, int lane, float* v) {
  if constexpr (VEC == 4) {
    u16x4v r = *reinterpret_cast<const u16x4v*>(base + (size_t)s * 256 + lane * 4);
    #pragma unroll
    for (int j = 0; j < 4; ++j) v[j] = bf2f(r[j]);
  } else {
    v[0] = bf2f(base[(size_t)s * 64 + lane]);
  }
}

template<int VEC, int GROUP>
__device__ __forceinline__ float edge_score(const float* xv, const float* xrv, const float* attv) {
  float p = 0.f;
  #pragma unroll
  for (int j = 0; j < VEC; ++j) {
    float tv = xv[j] + xrv[j];
    tv = fmaxf(tv, 0.2f * tv);     // leaky_relu slope 0.2
    p = fmaf(tv, attv[j], p);
  }
  #pragma unroll
  for (int msk = 1; msk < GROUP; msk <<= 1) p += __shfl_xor(p, msk);
  return p;
}

// one wave per dst node, LPT (degree-descending) order via perm;
// online softmax with deferred-max rescale (thr 8), 2-edge unroll.
template<int H, bool SELF, bool RELU>
__global__ __launch_bounds__(256) void edge_agg(
    const unsigned short* __restrict__ xl, const unsigned short* __restrict__ xr,
    const float* __restrict__ att, const float* __restrict__ bias,
    const int* __restrict__ rowstart, const int* __restrict__ csr,
    const int* __restrict__ perm,
    unsigned short* __restrict__ out, int N) {
  constexpr int F = H * 64;
  constexpr int VEC = F / 64;
  constexpr int GROUP = 64 / H;
  int wave = threadIdx.x >> 6, lane = threadIdx.x & 63;
  int gid = blockIdx.x * 4 + wave;
  if (gid >= N) return;
  int node = perm[gid];

  float attv[VEC];
  #pragma unroll
  for (int j = 0; j < VEC; ++j) attv[j] = att[lane * VEC + j];

  float xrv[VEC];
  load_row<VEC>(xr, node, lane, xrv);

  int s0 = rowstart[node], s1 = rowstart[node + 1];
  int end = s1 + (SELF ? 1 : 0);

  float m = 0.f, l = 0.f;
  float acc[VEC];
  #pragma unroll
  for (int j = 0; j < VEC; ++j) acc[j] = 0.f;

  int i = s0;
  if (i < end) {           // first edge: m := its score, w == 1
    int s = (i < s1) ? csr[i] : node;
    float xv[VEC];
    load_row<VEC>(xl, s, lane, xv);
    m = edge_score<VEC, GROUP>(xv, xrv, attv);
    l = 1.f;
    #pragma unroll
    for (int j = 0; j < VEC; ++j) acc[j] = xv[j];
    ++i;
  }
  for (; i + 2 <= end; i += 2) {
    int sA = (i < s1) ? csr[i] : node;
    int sB = (i + 1 < s1) ? csr[i + 1] : node;
    float xa[VEC], xb[VEC];
    load_row<VEC>(xl, sA, lane, xa);
    load_row<VEC>(xl, sB, lane, xb);
    float pA = edge_score<VEC, GROUP>(xa, xrv, attv);
    float pB = edge_score<VEC, GROUP>(xb, xrv, attv);
    float mx = fmaxf(pA, pB);
    if (__any(mx > m + 8.f)) {          // rare rescale
      float mn = fmaxf(m, mx);
      float sc = __expf(m - mn);
      l *= sc;
      #pragma unroll
      for (int j = 0; j < VEC; ++j) acc[j] *= sc;
      m = mn;
    }
    float wA = __expf(pA - m), wB = __expf(pB - m);
    l += wA + wB;
    #pragma unroll
    for (int j = 0; j < VEC; ++j) acc[j] = fmaf(wA, xa[j], fmaf(wB, xb[j], acc[j]));
  }
  if (i < end) {
    int s = (i < s1) ? csr[i] : node;
    float xv[VEC];
    load_row<VEC>(xl, s, lane, xv);
    float p = edge_score<VEC, GROUP>(xv, xrv, attv);
    if (__any(p > m + 8.f)) {
      float mn = fmaxf(m, p);
      float sc = __expf(m - mn);
      l *= sc;
      #pragma unroll
      for (int j = 0; j < VEC; ++j) acc[j] *= sc;
      m = mn;
    }
    float w = __expf(p - m);
    l += w;
    #pragma unroll
    for (int j = 0; j < VEC; ++j) acc[j] = fmaf(w, xv[j], acc[j]);
  }

  float rec = 1.f / (l + 1e-16f);
  if constexpr (VEC == 4) {
    u16x4v w4;
    #pragma unroll
    for (int j = 0; j < 4; ++j) {
      float o = fmaf(acc[j], rec, bias[lane * 4 + j]);
      if (RELU) o = fmaxf(o, 0.f);
      w4[j] = f2bf(o);
    }
    *reinterpret_cast<u16x4v*>(out + (size_t)node * 256 + lane * 4) = w4;
  } else {
    float o = fmaf(acc[0], rec, bias[lane]);
    if (RELU) o = fmaxf(o, 0.f);
    out[(size_t)node * 64 + lane] = f2bf(o);
  }
}

// ---------------- fused mean-pool + MLP + softmax: one block per graph ----------------
__global__ __launch_bounds__(256) void pool_mlp(
    const unsigned short* __restrict__ h, const int* __restrict__ batch,
    const float* __restrict__ w1, const float* __restrict__ b1,
    const float* __restrict__ w2, const float* __restrict__ b2,
    const float* __restrict__ w3, const float* __restrict__ b3,
    float* __restrict__ out, int N) {
  int g = blockIdx.x;
  // lower_bound(g), lower_bound(g+1) in sorted batch
  int lo = 0, hi = N;
  while (lo < hi) { int mid = (lo + hi) >> 1; if (batch[mid] < g) lo = mid + 1; else hi = mid; }
  int n0 = lo;
  hi = N;
  while (lo < hi) { int mid = (lo + hi) >> 1; if (batch[mid] < g + 1) lo = mid + 1; else hi = mid; }
  int n1 = lo;

  int t = threadIdx.x;
  int c2 = t & 31, r = t >> 5;     // 32 channel-pairs x 8 rows in flight
  float ax = 0.f, ay = 0.f;
  for (int n = n0 + r; n < n1; n += 8) {
    unsigned int u = *reinterpret_cast<const unsigned int*>(h + (size_t)n * 64 + c2 * 2);
    ax += bf2f((unsigned short)(u & 0xffffu));
    ay += bf2f((unsigned short)(u >> 16));
  }
  __shared__ float redx[8][32], redy[8][32];
  __shared__ float sh[64];
  redx[r][c2] = ax; redy[r][c2] = ay;
  __syncthreads();
  if (t < 64) {
    int lane = t;
    float s = 0.f;
    #pragma unroll
    for (int q = 0; q < 8; ++q) s += (lane & 1) ? redy[q][lane >> 1] : redx[q][lane >> 1];
    float cnt = fmaxf((float)(n1 - n0), 1.f);
    sh[lane] = s / cnt;
    float h1 = b1[lane];
    for (int k = 0; k < 64; ++k) h1 = fmaf(sh[k], w1[k * 64 + lane], h1);
    h1 = fmaxf(h1, 0.f);
    sh[lane] = h1;
    float h2 = b2[lane];
    for (int k = 0; k < 64; ++k) h2 = fmaf(sh[k], w2[k * 64 + lane], h2);
    h2 = fmaxf(h2, 0.f);
    sh[lane] = h2;
    float lg = -INFINITY;
    if (lane < 12) {
      lg = b3[lane];
      for (int k = 0; k < 64; ++k) lg = fmaf(sh[k], w3[k * 12 + lane], lg);
    }
    float mx = lg;
    #pragma unroll
    for (int msk = 1; msk < 64; msk <<= 1) mx = fmaxf(mx, __shfl_xor(mx, msk));
    float ex = (lane < 12) ? __expf(lg - mx) : 0.f;
    float sm = ex;
    #pragma unroll
    for (int msk = 1; msk < 64; msk <<= 1) sm += __shfl_xor(sm, msk);
    if (lane < 12) out[(size_t)g * 12 + lane] = ex / sm;
  }
}

// ---------------- host ----------------
extern "C" void kernel_launch(void* const* d_in, const int* in_sizes, int n_in,
                              void* d_out, int out_size, void* d_ws, size_t ws_size,
                              hipStream_t stream) {
  const float* x    = (const float*)d_in[0];
  const int* edge   = (const int*)d_in[1];
  const int* batch  = (const int*)d_in[2];
  const float* W1l  = (const float*)d_in[3];
  const float* W1r  = (const float*)d_in[4];
  const float* a1   = (const float*)d_in[5];
  const float* b1   = (const float*)d_in[6];
  const float* W2l  = (const float*)d_in[7];
  const float* W2r  = (const float*)d_in[8];
  const float* a2   = (const float*)d_in[9];
  const float* b2   = (const float*)d_in[10];
  const float* W3l  = (const float*)d_in[11];
  const float* W3r  = (const float*)d_in[12];
  const float* a3   = (const float*)d_in[13];
  const float* b3   = (const float*)d_in[14];
  const float* lw1  = (const float*)d_in[15];
  const float* lb1  = (const float*)d_in[16];
  const float* lw2  = (const float*)d_in[17];
  const float* lb2  = (const float*)d_in[18];
  const float* lw3  = (const float*)d_in[19];
  const float* lb3  = (const float*)d_in[20];

  const int E = in_sizes[1] / 2;
  const int N = in_sizes[2];
  const int F0 = in_sizes[0] / N;   // 128
  const int G = out_size / 12;      // 512
  const int* src = edge;
  const int* dst = edge + E;

  const int gx = (N + 127) / 128;
  const int Mpad = gx * 128;        // padded rows so GLL staging never reads OOB

  // workspace carve (256B aligned)
  char* p = (char*)d_ws;
  auto alloc = [&](size_t bytes) { char* q = p; p += (bytes + 255) & ~(size_t)255; return q; };
  unsigned short* bufA = (unsigned short*)alloc((size_t)Mpad * 256 * 2);
  unsigned short* bufB = (unsigned short*)alloc((size_t)Mpad * 256 * 2);
  unsigned short* bufH = (unsigned short*)alloc((size_t)Mpad * 256 * 2);
  unsigned short* Wt1L = (unsigned short*)alloc(128 * 256 * 2);
  unsigned short* Wt1R = (unsigned short*)alloc(128 * 256 * 2);
  unsigned short* Wt2L = (unsigned short*)alloc(256 * 256 * 2);
  unsigned short* Wt2R = (unsigned short*)alloc(256 * 256 * 2);
  unsigned short* Wt3L = (unsigned short*)alloc(256 * 64 * 2);
  unsigned short* Wt3R = (unsigned short*)alloc(256 * 64 * 2);
  int* counts   = (int*)alloc((size_t)N * 4);
  int* bcount   = (int*)alloc(256 * 4);
  int* dcur     = (int*)alloc(256 * 4);
  int* rowstart = (int*)alloc((size_t)(N + 1) * 4);
  int* cursor   = (int*)alloc((size_t)N * 4);
  int* perm     = (int*)alloc((size_t)N * 4);
  int* bsums    = (int*)alloc(4096 * 4);
  int* boffs    = (int*)alloc(4096 * 4);
  int* dummy    = (int*)alloc(64 * 4);
  int* csr      = (int*)alloc((size_t)E * 4);

  // ---- CSR by dst (built once, reused by all convs) ----
  hipMemsetAsync(counts, 0, (size_t)N * 4, stream);
  hipMemsetAsync(bcount, 0, 256 * 4, stream);
  hist_kernel<<<(E + 255) / 256, 256, 0, stream>>>(dst, counts, E);
  int nb = (N + 255) / 256;
  scan_block<<<nb, 256, 0, stream>>>(counts, rowstart, bsums, N);
  scan_block<<<1, 256, 0, stream>>>(bsums, boffs, dummy, nb);
  scan_add<<<nb, 256, 0, stream>>>(rowstart, boffs, cursor, N, E);
  scatter_kernel<<<(E + 255) / 256, 256, 0, stream>>>(src, dst, cursor, csr, E);

  // ---- LPT permutation: nodes in descending-degree order ----
  deg_hist<<<nb, 256, 0, stream>>>(rowstart, bcount, N);
  deg_offsets<<<1, 256, 0, stream>>>(bcount, dcur);
  deg_scatter<<<nb, 256, 0, stream>>>(rowstart, dcur, perm, N);

  // ---- all weight transposes in one launch ----
  {
    WPack wp;
    const float* ins[6] = {W1l, W1r, W2l, W2r, W3l, W3r};
    unsigned short* outs[6] = {Wt1L, Wt1R, Wt2L, Wt2R, Wt3L, Wt3R};
    int Ks[6] = {F0, F0, 256, 256, 256, 256};
    int Ns[6] = {256, 256, 256, 256, 64, 64};
    int acc0 = 0;
    for (int s = 0; s < 6; ++s) {
      wp.in[s] = ins[s]; wp.out[s] = outs[s]; wp.K[s] = Ks[s]; wp.Ncol[s] = Ns[s];
      wp.start[s] = acc0; acc0 += Ks[s] * Ns[s];
    }
    wp.start[6] = acc0;
    convert_all<<<(acc0 + 255) / 256, 256, 0, stream>>>(wp);
  }

  int ne = (N + 3) / 4;

  // ---- conv1: K=128, Ncol=256, no self loops, relu; A = x (f32, reg-staged) ----
  gemm_dual<128, 2, 2, true, false><<<dim3(gx, 2, 2), 256, 0, stream>>>(x, Wt1L, Wt1R, bufA, bufB, N, F0, 256);
  edge_agg<4, false, true><<<ne, 256, 0, stream>>>(bufA, bufB, a1, b1, rowstart, csr, perm, bufH, N);

  // ---- conv2: K=256, Ncol=256, self loops, relu; A = bufH (bf16, GLL) ----
  gemm_dual<128, 2, 2, false, true><<<dim3(gx, 2, 2), 256, 0, stream>>>(bufH, Wt2L, Wt2R, bufA, bufB, N, 256, 256);
  edge_agg<4, true, true><<<ne, 256, 0, stream>>>(bufA, bufB, a2, b2, rowstart, csr, perm, bufH, N);

  // ---- conv3: K=256, Ncol=64, self loops, no relu; A = bufH (bf16, GLL) ----
  gemm_dual<64, 4, 1, false, true><<<dim3(gx, 1, 2), 256, 0, stream>>>(bufH, Wt3L, Wt3R, bufA, bufB, N, 256, 64);
  edge_agg<1, true, false><<<ne, 256, 0, stream>>>(bufA, bufB, a3, b3, rowstart, csr, perm, bufH, N);

  // ---- fused mean pool + MLP head + softmax (one block per graph) ----
  pool_mlp<<<G, 256, 0, stream>>>(bufH, batch, lw1, lb1, lw2, lb2, lw3, lb3,
                                  (float*)d_out, N);
}

// Round 6
// 514.681 us; speedup vs baseline: 1.2492x; 1.2492x over previous
//
#include <hip/hip_runtime.h>
#include <hip/hip_bf16.h>
#include <cstdint>
#include <cstddef>

typedef short bf16x8 __attribute__((ext_vector_type(8)));
typedef float f32x4 __attribute__((ext_vector_type(4)));
typedef unsigned short u16x4v __attribute__((ext_vector_type(4)));

__device__ __forceinline__ float bf2f(unsigned short u) {
  union { unsigned int u; float f; } v; v.u = ((unsigned int)u) << 16; return v.f;
}
__device__ __forceinline__ unsigned short f2bf(float f) {
  union { float f; unsigned int u; } v; v.f = f;
  unsigned int r = v.u + 0x7fffu + ((v.u >> 16) & 1u);
  return (unsigned short)(r >> 16);
}
__device__ __forceinline__ int pack2(float a, float b) {
  return (int)f2bf(a) | ((int)f2bf(b) << 16);
}
// async global->LDS, 16B per lane; LDS dest is wave-uniform base + lane*16
__device__ __forceinline__ void gll16(const void* g, void* l) {
  __builtin_amdgcn_global_load_lds(
      (const __attribute__((address_space(1))) unsigned int*)g,
      (__attribute__((address_space(3))) unsigned int*)l, 16, 0, 0);
}

// ---------------- all-weight transpose+convert in ONE kernel ----------------
struct WPack {
  const float* in[6];
  unsigned short* out[6];
  int K[6], Ncol[6];
  int start[7];
};
__global__ __launch_bounds__(256) void convert_all(WPack p) {
  int idx = blockIdx.x * 256 + threadIdx.x;
  #pragma unroll
  for (int s = 0; s < 6; ++s) {
    if (idx >= p.start[s] && idx < p.start[s + 1]) {
      int lidx = idx - p.start[s];
      int k = lidx / p.Ncol[s], n = lidx % p.Ncol[s];
      p.out[s][n * p.K[s] + k] = f2bf(p.in[s][lidx]);
    }
  }
}

// ---------------- GEMM: C[M,Ncol] = A[M,K] @ Wt[Ncol,K]^T (f32 acc, bf16 out)
// AF32: A is f32, reg-staged+converted. GLL: A,B bf16 via global_load_lds
// (requires A rows valid up to gx*128 — buffers are padded).
template<int BN, int WAVES_M, int WAVES_N, bool AF32, bool GLL>
__global__ __launch_bounds__(256) void gemm_dual(
    const void* __restrict__ Av,
    const unsigned short* __restrict__ BtL, const unsigned short* __restrict__ BtR,
    unsigned short* __restrict__ outL, unsigned short* __restrict__ outR,
    int M, int K, int Ncol) {
  constexpr int BM = 128, BK = 64;
  constexpr int WTM = BM / WAVES_M, WTN = BN / WAVES_N;
  constexpr int MR = WTM / 16, NR = WTN / 16;
  const unsigned short* __restrict__ Bt = blockIdx.z ? BtR : BtL;
  unsigned short* __restrict__ outp = blockIdx.z ? outR : outL;

  __shared__ alignas(16) unsigned short lAt[BM * BK];
  __shared__ alignas(16) unsigned short lBt[BN * BK];

  int t = threadIdx.x;
  int lane = t & 63, wid = t >> 6;
  int wm = wid / WAVES_N, wn = wid % WAVES_N;
  int rowBase = blockIdx.x * BM;
  int colBase = blockIdx.y * BN;

  f32x4 acc[MR][NR] = {};

  for (int k0 = 0; k0 < K; k0 += BK) {
    if constexpr (GLL) {
      const unsigned short* A = (const unsigned short*)Av;
      #pragma unroll
      for (int p = 0; p < BM / 32; ++p) {
        int chunk = wid * (BM / 32) + p;
        int row = chunk * 8 + (lane >> 3);
        int c = (lane & 7) ^ (row & 7);   // pre-swizzled source, linear LDS dest
        gll16(A + (size_t)(rowBase + row) * K + k0 + c * 8, &lAt[chunk * 512]);
      }
      #pragma unroll
      for (int p = 0; p < BN / 32; ++p) {
        int chunk = wid * (BN / 32) + p;
        int row = chunk * 8 + (lane >> 3);
        int c = (lane & 7) ^ (row & 7);
        gll16(Bt + (size_t)(colBase + row) * K + k0 + c * 8, &lBt[chunk * 512]);
      }
    } else {
      #pragma unroll
      for (int p = 0; p < (BM * 8) / 256; ++p) {
        int lin = p * 256 + t;
        int row = lin >> 3, c = lin & 7;
        int gr = rowBase + row;
        int4 w = make_int4(0, 0, 0, 0);
        if constexpr (AF32) {
          const float* A = (const float*)Av;
          if (gr < M) {
            const float* ap = A + (size_t)gr * K + k0 + c * 8;
            f32x4 f0 = *reinterpret_cast<const f32x4*>(ap);
            f32x4 f1 = *reinterpret_cast<const f32x4*>(ap + 4);
            w.x = pack2(f0[0], f0[1]); w.y = pack2(f0[2], f0[3]);
            w.z = pack2(f1[0], f1[1]); w.w = pack2(f1[2], f1[3]);
          }
        } else {
          const unsigned short* A = (const unsigned short*)Av;
          if (gr < M) w = *reinterpret_cast<const int4*>(A + (size_t)gr * K + k0 + c * 8);
        }
        *reinterpret_cast<int4*>(&lAt[row * 64 + ((c ^ (row & 7)) * 8)]) = w;
      }
      #pragma unroll
      for (int p = 0; p < (BN * 8) / 256; ++p) {
        int lin = p * 256 + t;
        int row = lin >> 3, c = lin & 7;
        int4 v = *reinterpret_cast<const int4*>(Bt + (size_t)(colBase + row) * K + k0 + c * 8);
        *reinterpret_cast<int4*>(&lBt[row * 64 + ((c ^ (row & 7)) * 8)]) = v;
      }
    }
    __syncthreads();
    #pragma unroll
    for (int kk = 0; kk < 2; ++kk) {
      bf16x8 af[MR], bfr[NR];
      int cidx = kk * 4 + (lane >> 4);
      #pragma unroll
      for (int mi = 0; mi < MR; ++mi) {
        int row = wm * WTM + mi * 16 + (lane & 15);
        af[mi] = *reinterpret_cast<const bf16x8*>(&lAt[row * 64 + ((cidx ^ (row & 7)) * 8)]);
      }
      #pragma unroll
      for (int ni = 0; ni < NR; ++ni) {
        int row = wn * WTN + ni * 16 + (lane & 15);
        bfr[ni] = *reinterpret_cast<const bf16x8*>(&lBt[row * 64 + ((cidx ^ (row & 7)) * 8)]);
      }
      #pragma unroll
      for (int mi = 0; mi < MR; ++mi)
        #pragma unroll
        for (int ni = 0; ni < NR; ++ni)
          acc[mi][ni] = __builtin_amdgcn_mfma_f32_16x16x32_bf16(af[mi], bfr[ni], acc[mi][ni], 0, 0, 0);
    }
    __syncthreads();
  }
  #pragma unroll
  for (int mi = 0; mi < MR; ++mi)
    #pragma unroll
    for (int ni = 0; ni < NR; ++ni) {
      int col = colBase + wn * WTN + ni * 16 + (lane & 15);
      #pragma unroll
      for (int r = 0; r < 4; ++r) {
        int row = rowBase + wm * WTM + mi * 16 + (lane >> 4) * 4 + r;
        if (row < M) outp[(size_t)row * Ncol + col] = f2bf(acc[mi][ni][r]);
      }
    }
}

// ---------------- CSR build ----------------
__global__ __launch_bounds__(256) void hist_kernel(const int* __restrict__ dst, int* __restrict__ counts, int E) {
  int e = blockIdx.x * 256 + threadIdx.x;
  if (e < E) atomicAdd(&counts[dst[e]], 1);
}

__global__ __launch_bounds__(256) void scan_block(const int* __restrict__ in, int* __restrict__ out,
                                                  int* __restrict__ sums, int n) {
  int i = blockIdx.x * 256 + threadIdx.x;
  int lane = threadIdx.x & 63, wid = threadIdx.x >> 6;
  int v = (i < n) ? in[i] : 0;
  int s = v;
  #pragma unroll
  for (int d = 1; d < 64; d <<= 1) { int tt = __shfl_up(s, d); if (lane >= d) s += tt; }
  __shared__ int wsum[4];
  if (lane == 63) wsum[wid] = s;
  __syncthreads();
  int off = 0;
  for (int w = 0; w < wid; ++w) off += wsum[w];
  if (i < n) out[i] = off + s - v;  // exclusive
  if (threadIdx.x == 255) sums[blockIdx.x] = off + s;
}

__global__ __launch_bounds__(256) void scan_add(int* __restrict__ rs, const int* __restrict__ boffs,
                                                int* __restrict__ cursor, int n, int E) {
  int i = blockIdx.x * 256 + threadIdx.x;
  if (i < n) {
    int v = rs[i] + boffs[blockIdx.x];
    rs[i] = v;
    cursor[i] = v;
  }
  if (i == 0) rs[n] = E;
}

__global__ __launch_bounds__(256) void scatter_kernel(const int* __restrict__ src, const int* __restrict__ dst,
                                                      int* __restrict__ cursor, int* __restrict__ csr, int E) {
  int e = blockIdx.x * 256 + threadIdx.x;
  if (e < E) {
    int p = atomicAdd(&cursor[dst[e]], 1);
    csr[p] = src[e];
  }
}

// ---------------- LPT permutation via contention-free counting sort ----------------
// A: per-block LDS hist; <=1 global atomic per (block, nonzero bin).
__global__ __launch_bounds__(256) void deg_reserve(const int* __restrict__ rs, int* __restrict__ binTotal,
                                                   int* __restrict__ blockBase, int N) {
  __shared__ int lh[256];
  lh[threadIdx.x] = 0;
  __syncthreads();
  int n = blockIdx.x * 256 + threadIdx.x;
  if (n < N) {
    int d = rs[n + 1] - rs[n];
    if (d > 255) d = 255;
    atomicAdd(&lh[d], 1);
  }
  __syncthreads();
  int c = lh[threadIdx.x];
  blockBase[blockIdx.x * 256 + threadIdx.x] = c ? atomicAdd(&binTotal[threadIdx.x], c) : 0;
}

// binStart[d] = sum_{d'>d} binTotal[d']  (descending-degree exclusive offsets)
__global__ __launch_bounds__(256) void deg_offsets(const int* __restrict__ binTotal, int* __restrict__ binStart) {
  int t = threadIdx.x;
  int lane = t & 63, w = t >> 6;
  int v = binTotal[255 - t];
  int s = v;
  #pragma unroll
  for (int d1 = 1; d1 < 64; d1 <<= 1) { int tt = __shfl_up(s, d1); if (lane >= d1) s += tt; }
  __shared__ int ws[4];
  if (lane == 63) ws[w] = s;
  __syncthreads();
  int off = 0;
  for (int u = 0; u < w; ++u) off += ws[u];
  binStart[255 - t] = off + s - v;
}

// B: LDS cursors seeded with binStart + this block's reservation; LDS atomics only.
__global__ __launch_bounds__(256) void deg_place(const int* __restrict__ rs, const int* __restrict__ binStart,
                                                 const int* __restrict__ blockBase, int* __restrict__ perm, int N) {
  __shared__ int lcur[256];
  lcur[threadIdx.x] = binStart[threadIdx.x] + blockBase[blockIdx.x * 256 + threadIdx.x];
  __syncthreads();
  int n = blockIdx.x * 256 + threadIdx.x;
  if (n < N) {
    int d = rs[n + 1] - rs[n];
    if (d > 255) d = 255;
    perm[atomicAdd(&lcur[d], 1)] = n;
  }
}

// ---------------- edge aggregation helpers ----------------
template<int VEC>
__device__ __forceinline__ void load_row(const unsigned short* __restrict__ base,
                                         int s, int lane, float* v) {
  if constexpr (VEC == 4) {
    u16x4v r = *reinterpret_cast<const u16x4v*>(base + (size_t)s * 256 + lane * 4);
    #pragma unroll
    for (int j = 0; j < 4; ++j) v[j] = bf2f(r[j]);
  } else {
    v[0] = bf2f(base[(size_t)s * 64 + lane]);
  }
}

template<int VEC, int GROUP>
__device__ __forceinline__ float edge_score(const float* xv, const float* xrv, const float* attv) {
  float p = 0.f;
  #pragma unroll
  for (int j = 0; j < VEC; ++j) {
    float tv = xv[j] + xrv[j];
    tv = fmaxf(tv, 0.2f * tv);     // leaky_relu slope 0.2
    p = fmaf(tv, attv[j], p);
  }
  #pragma unroll
  for (int msk = 1; msk < GROUP; msk <<= 1) p += __shfl_xor(p, msk);
  return p;
}

// one wave per dst node, LPT (degree-descending) order via perm;
// online softmax with deferred-max rescale (thr 8), 2-edge unroll.
template<int H, bool SELF, bool RELU>
__global__ __launch_bounds__(256) void edge_agg(
    const unsigned short* __restrict__ xl, const unsigned short* __restrict__ xr,
    const float* __restrict__ att, const float* __restrict__ bias,
    const int* __restrict__ rowstart, const int* __restrict__ csr,
    const int* __restrict__ perm,
    unsigned short* __restrict__ out, int N) {
  constexpr int F = H * 64;
  constexpr int VEC = F / 64;
  constexpr int GROUP = 64 / H;
  int wave = threadIdx.x >> 6, lane = threadIdx.x & 63;
  int gid = blockIdx.x * 4 + wave;
  if (gid >= N) return;
  int node = perm[gid];

  float attv[VEC];
  #pragma unroll
  for (int j = 0; j < VEC; ++j) attv[j] = att[lane * VEC + j];

  float xrv[VEC];
  load_row<VEC>(xr, node, lane, xrv);

  int s0 = rowstart[node], s1 = rowstart[node + 1];
  int end = s1 + (SELF ? 1 : 0);

  float m = 0.f, l = 0.f;
  float acc[VEC];
  #pragma unroll
  for (int j = 0; j < VEC; ++j) acc[j] = 0.f;

  int i = s0;
  if (i < end) {           // first edge: m := its score, w == 1
    int s = (i < s1) ? csr[i] : node;
    float xv[VEC];
    load_row<VEC>(xl, s, lane, xv);
    m = edge_score<VEC, GROUP>(xv, xrv, attv);
    l = 1.f;
    #pragma unroll
    for (int j = 0; j < VEC; ++j) acc[j] = xv[j];
    ++i;
  }
  for (; i + 2 <= end; i += 2) {
    int sA = (i < s1) ? csr[i] : node;
    int sB = (i + 1 < s1) ? csr[i + 1] : node;
    float xa[VEC], xb[VEC];
    load_row<VEC>(xl, sA, lane, xa);
    load_row<VEC>(xl, sB, lane, xb);
    float pA = edge_score<VEC, GROUP>(xa, xrv, attv);
    float pB = edge_score<VEC, GROUP>(xb, xrv, attv);
    float mx = fmaxf(pA, pB);
    if (__any(mx > m + 8.f)) {          // rare rescale
      float mn = fmaxf(m, mx);
      float sc = __expf(m - mn);
      l *= sc;
      #pragma unroll
      for (int j = 0; j < VEC; ++j) acc[j] *= sc;
      m = mn;
    }
    float wA = __expf(pA - m), wB = __expf(pB - m);
    l += wA + wB;
    #pragma unroll
    for (int j = 0; j < VEC; ++j) acc[j] = fmaf(wA, xa[j], fmaf(wB, xb[j], acc[j]));
  }
  if (i < end) {
    int s = (i < s1) ? csr[i] : node;
    float xv[VEC];
    load_row<VEC>(xl, s, lane, xv);
    float p = edge_score<VEC, GROUP>(xv, xrv, attv);
    if (__any(p > m + 8.f)) {
      float mn = fmaxf(m, p);
      float sc = __expf(m - mn);
      l *= sc;
      #pragma unroll
      for (int j = 0; j < VEC; ++j) acc[j] *= sc;
      m = mn;
    }
    float w = __expf(p - m);
    l += w;
    #pragma unroll
    for (int j = 0; j < VEC; ++j) acc[j] = fmaf(w, xv[j], acc[j]);
  }

  float rec = 1.f / (l + 1e-16f);
  if constexpr (VEC == 4) {
    u16x4v w4;
    #pragma unroll
    for (int j = 0; j < 4; ++j) {
      float o = fmaf(acc[j], rec, bias[lane * 4 + j]);
      if (RELU) o = fmaxf(o, 0.f);
      w4[j] = f2bf(o);
    }
    *reinterpret_cast<u16x4v*>(out + (size_t)node * 256 + lane * 4) = w4;
  } else {
    float o = fmaf(acc[0], rec, bias[lane]);
    if (RELU) o = fmaxf(o, 0.f);
    out[(size_t)node * 64 + lane] = f2bf(o);
  }
}

// ---------------- fused mean-pool + MLP + softmax: one block per graph ----------------
__global__ __launch_bounds__(256) void pool_mlp(
    const unsigned short* __restrict__ h, const int* __restrict__ batch,
    const float* __restrict__ w1, const float* __restrict__ b1,
    const float* __restrict__ w2, const float* __restrict__ b2,
    const float* __restrict__ w3, const float* __restrict__ b3,
    float* __restrict__ out, int N) {
  int g = blockIdx.x;
  int lo = 0, hi = N;
  while (lo < hi) { int mid = (lo + hi) >> 1; if (batch[mid] < g) lo = mid + 1; else hi = mid; }
  int n0 = lo;
  hi = N;
  while (lo < hi) { int mid = (lo + hi) >> 1; if (batch[mid] < g + 1) lo = mid + 1; else hi = mid; }
  int n1 = lo;

  int t = threadIdx.x;
  int c2 = t & 31, r = t >> 5;     // 32 channel-pairs x 8 rows in flight
  float ax = 0.f, ay = 0.f;
  for (int n = n0 + r; n < n1; n += 8) {
    unsigned int u = *reinterpret_cast<const unsigned int*>(h + (size_t)n * 64 + c2 * 2);
    ax += bf2f((unsigned short)(u & 0xffffu));
    ay += bf2f((unsigned short)(u >> 16));
  }
  __shared__ float redx[8][32], redy[8][32];
  __shared__ float sh[64];
  redx[r][c2] = ax; redy[r][c2] = ay;
  __syncthreads();
  if (t < 64) {
    int lane = t;
    float s = 0.f;
    #pragma unroll
    for (int q = 0; q < 8; ++q) s += (lane & 1) ? redy[q][lane >> 1] : redx[q][lane >> 1];
    float cnt = fmaxf((float)(n1 - n0), 1.f);
    sh[lane] = s / cnt;
    float h1 = b1[lane];
    for (int k = 0; k < 64; ++k) h1 = fmaf(sh[k], w1[k * 64 + lane], h1);
    h1 = fmaxf(h1, 0.f);
    sh[lane] = h1;
    float h2 = b2[lane];
    for (int k = 0; k < 64; ++k) h2 = fmaf(sh[k], w2[k * 64 + lane], h2);
    h2 = fmaxf(h2, 0.f);
    sh[lane] = h2;
    float lg = -INFINITY;
    if (lane < 12) {
      lg = b3[lane];
      for (int k = 0; k < 64; ++k) lg = fmaf(sh[k], w3[k * 12 + lane], lg);
    }
    float mx = lg;
    #pragma unroll
    for (int msk = 1; msk < 64; msk <<= 1) mx = fmaxf(mx, __shfl_xor(mx, msk));
    float ex = (lane < 12) ? __expf(lg - mx) : 0.f;
    float sm = ex;
    #pragma unroll
    for (int msk = 1; msk < 64; msk <<= 1) sm += __shfl_xor(sm, msk);
    if (lane < 12) out[(size_t)g * 12 + lane] = ex / sm;
  }
}

// ---------------- host ----------------
extern "C" void kernel_launch(void* const* d_in, const int* in_sizes, int n_in,
                              void* d_out, int out_size, void* d_ws, size_t ws_size,
                              hipStream_t stream) {
  const float* x    = (const float*)d_in[0];
  const int* edge   = (const int*)d_in[1];
  const int* batch  = (const int*)d_in[2];
  const float* W1l  = (const float*)d_in[3];
  const float* W1r  = (const float*)d_in[4];
  const float* a1   = (const float*)d_in[5];
  const float* b1   = (const float*)d_in[6];
  const float* W2l  = (const float*)d_in[7];
  const float* W2r  = (const float*)d_in[8];
  const float* a2   = (const float*)d_in[9];
  const float* b2   = (const float*)d_in[10];
  const float* W3l  = (const float*)d_in[11];
  const float* W3r  = (const float*)d_in[12];
  const float* a3   = (const float*)d_in[13];
  const float* b3   = (const float*)d_in[14];
  const float* lw1  = (const float*)d_in[15];
  const float* lb1  = (const float*)d_in[16];
  const float* lw2  = (const float*)d_in[17];
  const float* lb2  = (const float*)d_in[18];
  const float* lw3  = (const float*)d_in[19];
  const float* lb3  = (const float*)d_in[20];

  const int E = in_sizes[1] / 2;
  const int N = in_sizes[2];
  const int F0 = in_sizes[0] / N;   // 128
  const int G = out_size / 12;      // 512
  const int* src = edge;
  const int* dst = edge + E;

  const int gx = (N + 127) / 128;
  const int Mpad = gx * 128;        // padded rows so GLL staging never reads OOB
  const int nb = (N + 255) / 256;

  // workspace carve (256B aligned)
  char* p = (char*)d_ws;
  auto alloc = [&](size_t bytes) { char* q = p; p += (bytes + 255) & ~(size_t)255; return q; };
  unsigned short* bufA = (unsigned short*)alloc((size_t)Mpad * 256 * 2);
  unsigned short* bufB = (unsigned short*)alloc((size_t)Mpad * 256 * 2);
  unsigned short* bufH = (unsigned short*)alloc((size_t)Mpad * 256 * 2);
  unsigned short* Wt1L = (unsigned short*)alloc(128 * 256 * 2);
  unsigned short* Wt1R = (unsigned short*)alloc(128 * 256 * 2);
  unsigned short* Wt2L = (unsigned short*)alloc(256 * 256 * 2);
  unsigned short* Wt2R = (unsigned short*)alloc(256 * 256 * 2);
  unsigned short* Wt3L = (unsigned short*)alloc(256 * 64 * 2);
  unsigned short* Wt3R = (unsigned short*)alloc(256 * 64 * 2);
  int* counts    = (int*)alloc((size_t)N * 4);
  int* binTotal  = (int*)alloc(256 * 4);
  int* binStart  = (int*)alloc(256 * 4);
  int* blockBase = (int*)alloc((size_t)nb * 256 * 4);
  int* rowstart  = (int*)alloc((size_t)(N + 1) * 4);
  int* cursor    = (int*)alloc((size_t)N * 4);
  int* perm      = (int*)alloc((size_t)N * 4);
  int* bsums     = (int*)alloc(4096 * 4);
  int* boffs     = (int*)alloc(4096 * 4);
  int* dummy     = (int*)alloc(64 * 4);
  int* csr       = (int*)alloc((size_t)E * 4);

  // ---- CSR by dst (built once, reused by all convs) ----
  hipMemsetAsync(counts, 0, (size_t)N * 4, stream);
  hipMemsetAsync(binTotal, 0, 256 * 4, stream);
  hist_kernel<<<(E + 255) / 256, 256, 0, stream>>>(dst, counts, E);
  scan_block<<<nb, 256, 0, stream>>>(counts, rowstart, bsums, N);
  scan_block<<<1, 256, 0, stream>>>(bsums, boffs, dummy, nb);
  scan_add<<<nb, 256, 0, stream>>>(rowstart, boffs, cursor, N, E);
  scatter_kernel<<<(E + 255) / 256, 256, 0, stream>>>(src, dst, cursor, csr, E);

  // ---- LPT permutation (contention-free counting sort) ----
  deg_reserve<<<nb, 256, 0, stream>>>(rowstart, binTotal, blockBase, N);
  deg_offsets<<<1, 256, 0, stream>>>(binTotal, binStart);
  deg_place<<<nb, 256, 0, stream>>>(rowstart, binStart, blockBase, perm, N);

  // ---- all weight transposes in one launch ----
  {
    WPack wp;
    const float* ins[6] = {W1l, W1r, W2l, W2r, W3l, W3r};
    unsigned short* outs[6] = {Wt1L, Wt1R, Wt2L, Wt2R, Wt3L, Wt3R};
    int Ks[6] = {F0, F0, 256, 256, 256, 256};
    int Ns[6] = {256, 256, 256, 256, 64, 64};
    int acc0 = 0;
    for (int s = 0; s < 6; ++s) {
      wp.in[s] = ins[s]; wp.out[s] = outs[s]; wp.K[s] = Ks[s]; wp.Ncol[s] = Ns[s];
      wp.start[s] = acc0; acc0 += Ks[s] * Ns[s];
    }
    wp.start[6] = acc0;
    convert_all<<<(acc0 + 255) / 256, 256, 0, stream>>>(wp);
  }

  int ne = (N + 3) / 4;

  // ---- conv1: K=128, Ncol=256, no self loops, relu; A = x (f32, reg-staged) ----
  gemm_dual<128, 2, 2, true, false><<<dim3(gx, 2, 2), 256, 0, stream>>>(x, Wt1L, Wt1R, bufA, bufB, N, F0, 256);
  edge_agg<4, false, true><<<ne, 256, 0, stream>>>(bufA, bufB, a1, b1, rowstart, csr, perm, bufH, N);

  // ---- conv2: K=256, Ncol=256, self loops, relu; A = bufH (bf16, GLL) ----
  gemm_dual<128, 2, 2, false, true><<<dim3(gx, 2, 2), 256, 0, stream>>>(bufH, Wt2L, Wt2R, bufA, bufB, N, 256, 256);
  edge_agg<4, true, true><<<ne, 256, 0, stream>>>(bufA, bufB, a2, b2, rowstart, csr, perm, bufH, N);

  // ---- conv3: K=256, Ncol=64, self loops, no relu; A = bufH (bf16, GLL) ----
  gemm_dual<64, 4, 1, false, true><<<dim3(gx, 1, 2), 256, 0, stream>>>(bufH, Wt3L, Wt3R, bufA, bufB, N, 256, 64);
  edge_agg<1, true, false><<<ne, 256, 0, stream>>>(bufA, bufB, a3, b3, rowstart, csr, perm, bufH, N);

  // ---- fused mean pool + MLP head + softmax (one block per graph) ----
  pool_mlp<<<G, 256, 0, stream>>>(bufH, batch, lw1, lb1, lw2, lb2, lw3, lb3,
                                  (float*)d_out, N);
}

// Round 7
// 463.764 us; speedup vs baseline: 1.3864x; 1.1098x over previous
//
#include <hip/hip_runtime.h>
#include <hip/hip_bf16.h>
#include <cstdint>
#include <cstddef>

typedef short bf16x8 __attribute__((ext_vector_type(8)));
typedef float f32x4 __attribute__((ext_vector_type(4)));
typedef unsigned short u16x4v __attribute__((ext_vector_type(4)));

__device__ __forceinline__ float bf2f(unsigned short u) {
  union { unsigned int u; float f; } v; v.u = ((unsigned int)u) << 16; return v.f;
}
__device__ __forceinline__ unsigned short f2bf(float f) {
  union { float f; unsigned int u; } v; v.f = f;
  unsigned int r = v.u + 0x7fffu + ((v.u >> 16) & 1u);
  return (unsigned short)(r >> 16);
}
__device__ __forceinline__ int pack2(float a, float b) {
  return (int)f2bf(a) | ((int)f2bf(b) << 16);
}
// async global->LDS, 16B per lane
__device__ __forceinline__ void gll16(const void* g, void* l) {
  __builtin_amdgcn_global_load_lds(
      (const __attribute__((address_space(1))) unsigned int*)g,
      (__attribute__((address_space(3))) unsigned int*)l, 16, 0, 0);
}
// DPP rotate-within-row16 + add (VALU latency, replaces ds_swizzle shuffles)
template<int CTRL>
__device__ __forceinline__ float dpp_ror_add(float p) {
  int t = __builtin_amdgcn_update_dpp(0, __builtin_bit_cast(int, p), CTRL, 0xf, 0xf, true);
  return p + __builtin_bit_cast(float, t);
}
__device__ __forceinline__ float row16_sum(float p) {
  p = dpp_ror_add<0x121>(p);   // ror 1
  p = dpp_ror_add<0x122>(p);   // ror 2
  p = dpp_ror_add<0x124>(p);   // ror 4
  p = dpp_ror_add<0x128>(p);   // ror 8
  return p;
}

// ---------------- all-weight transpose+convert in ONE kernel ----------------
struct WPack {
  const float* in[6];
  unsigned short* out[6];
  int K[6], Ncol[6];
  int start[7];
};
__global__ __launch_bounds__(256) void convert_all(WPack p) {
  int idx = blockIdx.x * 256 + threadIdx.x;
  #pragma unroll
  for (int s = 0; s < 6; ++s) {
    if (idx >= p.start[s] && idx < p.start[s + 1]) {
      int lidx = idx - p.start[s];
      int k = lidx / p.Ncol[s], n = lidx % p.Ncol[s];
      p.out[s][n * p.K[s] + k] = f2bf(p.in[s][lidx]);
    }
  }
}

// ---------------- GEMM: C[M,Ncol] = A[M,K] @ Wt[Ncol,K]^T (f32 acc, bf16 out)
template<int BN, int WAVES_M, int WAVES_N, bool AF32, bool GLL>
__global__ __launch_bounds__(256) void gemm_dual(
    const void* __restrict__ Av,
    const unsigned short* __restrict__ BtL, const unsigned short* __restrict__ BtR,
    unsigned short* __restrict__ outL, unsigned short* __restrict__ outR,
    int M, int K, int Ncol) {
  constexpr int BM = 128, BK = 64;
  constexpr int WTM = BM / WAVES_M, WTN = BN / WAVES_N;
  constexpr int MR = WTM / 16, NR = WTN / 16;
  const unsigned short* __restrict__ Bt = blockIdx.z ? BtR : BtL;
  unsigned short* __restrict__ outp = blockIdx.z ? outR : outL;

  __shared__ alignas(16) unsigned short lAt[BM * BK];
  __shared__ alignas(16) unsigned short lBt[BN * BK];

  int t = threadIdx.x;
  int lane = t & 63, wid = t >> 6;
  int wm = wid / WAVES_N, wn = wid % WAVES_N;
  int rowBase = blockIdx.x * BM;
  int colBase = blockIdx.y * BN;

  f32x4 acc[MR][NR] = {};

  for (int k0 = 0; k0 < K; k0 += BK) {
    if constexpr (GLL) {
      const unsigned short* A = (const unsigned short*)Av;
      #pragma unroll
      for (int p = 0; p < BM / 32; ++p) {
        int chunk = wid * (BM / 32) + p;
        int row = chunk * 8 + (lane >> 3);
        int c = (lane & 7) ^ (row & 7);   // pre-swizzled source, linear LDS dest
        gll16(A + (size_t)(rowBase + row) * K + k0 + c * 8, &lAt[chunk * 512]);
      }
      #pragma unroll
      for (int p = 0; p < BN / 32; ++p) {
        int chunk = wid * (BN / 32) + p;
        int row = chunk * 8 + (lane >> 3);
        int c = (lane & 7) ^ (row & 7);
        gll16(Bt + (size_t)(colBase + row) * K + k0 + c * 8, &lBt[chunk * 512]);
      }
    } else {
      #pragma unroll
      for (int p = 0; p < (BM * 8) / 256; ++p) {
        int lin = p * 256 + t;
        int row = lin >> 3, c = lin & 7;
        int gr = rowBase + row;
        int4 w = make_int4(0, 0, 0, 0);
        if constexpr (AF32) {
          const float* A = (const float*)Av;
          if (gr < M) {
            const float* ap = A + (size_t)gr * K + k0 + c * 8;
            f32x4 f0 = *reinterpret_cast<const f32x4*>(ap);
            f32x4 f1 = *reinterpret_cast<const f32x4*>(ap + 4);
            w.x = pack2(f0[0], f0[1]); w.y = pack2(f0[2], f0[3]);
            w.z = pack2(f1[0], f1[1]); w.w = pack2(f1[2], f1[3]);
          }
        } else {
          const unsigned short* A = (const unsigned short*)Av;
          if (gr < M) w = *reinterpret_cast<const int4*>(A + (size_t)gr * K + k0 + c * 8);
        }
        *reinterpret_cast<int4*>(&lAt[row * 64 + ((c ^ (row & 7)) * 8)]) = w;
      }
      #pragma unroll
      for (int p = 0; p < (BN * 8) / 256; ++p) {
        int lin = p * 256 + t;
        int row = lin >> 3, c = lin & 7;
        int4 v = *reinterpret_cast<const int4*>(Bt + (size_t)(colBase + row) * K + k0 + c * 8);
        *reinterpret_cast<int4*>(&lBt[row * 64 + ((c ^ (row & 7)) * 8)]) = v;
      }
    }
    __syncthreads();
    #pragma unroll
    for (int kk = 0; kk < 2; ++kk) {
      bf16x8 af[MR], bfr[NR];
      int cidx = kk * 4 + (lane >> 4);
      #pragma unroll
      for (int mi = 0; mi < MR; ++mi) {
        int row = wm * WTM + mi * 16 + (lane & 15);
        af[mi] = *reinterpret_cast<const bf16x8*>(&lAt[row * 64 + ((cidx ^ (row & 7)) * 8)]);
      }
      #pragma unroll
      for (int ni = 0; ni < NR; ++ni) {
        int row = wn * WTN + ni * 16 + (lane & 15);
        bfr[ni] = *reinterpret_cast<const bf16x8*>(&lBt[row * 64 + ((cidx ^ (row & 7)) * 8)]);
      }
      #pragma unroll
      for (int mi = 0; mi < MR; ++mi)
        #pragma unroll
        for (int ni = 0; ni < NR; ++ni)
          acc[mi][ni] = __builtin_amdgcn_mfma_f32_16x16x32_bf16(af[mi], bfr[ni], acc[mi][ni], 0, 0, 0);
    }
    __syncthreads();
  }
  #pragma unroll
  for (int mi = 0; mi < MR; ++mi)
    #pragma unroll
    for (int ni = 0; ni < NR; ++ni) {
      int col = colBase + wn * WTN + ni * 16 + (lane & 15);
      #pragma unroll
      for (int r = 0; r < 4; ++r) {
        int row = rowBase + wm * WTM + mi * 16 + (lane >> 4) * 4 + r;
        if (row < M) outp[(size_t)row * Ncol + col] = f2bf(acc[mi][ni][r]);
      }
    }
}

// ---------------- CSR build (+ LPT bits folded in) ----------------
__global__ __launch_bounds__(256) void hist_kernel(const int* __restrict__ dst, int* __restrict__ counts, int E) {
  int e = blockIdx.x * 256 + threadIdx.x;
  if (e < E) atomicAdd(&counts[dst[e]], 1);
}

// block-level exclusive scan of counts + per-block degree histogram + bin reservation
__global__ __launch_bounds__(256) void scan_block_deg(
    const int* __restrict__ in, int* __restrict__ out, int* __restrict__ sums,
    int* __restrict__ binTotal, int* __restrict__ blockBase, int n) {
  __shared__ int lh[256];
  __shared__ int wsum[4];
  lh[threadIdx.x] = 0;
  __syncthreads();
  int i = blockIdx.x * 256 + threadIdx.x;
  int lane = threadIdx.x & 63, wid = threadIdx.x >> 6;
  int v = (i < n) ? in[i] : 0;
  if (i < n) atomicAdd(&lh[v < 255 ? v : 255], 1);
  int s = v;
  #pragma unroll
  for (int d = 1; d < 64; d <<= 1) { int tt = __shfl_up(s, d); if (lane >= d) s += tt; }
  if (lane == 63) wsum[wid] = s;
  __syncthreads();
  int off = 0;
  for (int w = 0; w < wid; ++w) off += wsum[w];
  if (i < n) out[i] = off + s - v;  // exclusive
  if (threadIdx.x == 255) sums[blockIdx.x] = off + s;
  int c = lh[threadIdx.x];
  blockBase[blockIdx.x * 256 + threadIdx.x] = c ? atomicAdd(&binTotal[threadIdx.x], c) : 0;
}

// second-level scan of block sums + descending-degree bin offsets (one block)
__global__ __launch_bounds__(256) void scan2_offsets(
    const int* __restrict__ bsums, int* __restrict__ boffs,
    const int* __restrict__ binTotal, int* __restrict__ binStart, int n) {
  __shared__ int ws[4];
  int t = threadIdx.x;
  int lane = t & 63, w = t >> 6;
  {
    int v = (t < n) ? bsums[t] : 0;
    int s = v;
    #pragma unroll
    for (int d = 1; d < 64; d <<= 1) { int tt = __shfl_up(s, d); if (lane >= d) s += tt; }
    if (lane == 63) ws[w] = s;
    __syncthreads();
    int off = 0;
    for (int u = 0; u < w; ++u) off += ws[u];
    if (t < n) boffs[t] = off + s - v;
    __syncthreads();
  }
  {
    int v = binTotal[255 - t];
    int s = v;
    #pragma unroll
    for (int d = 1; d < 64; d <<= 1) { int tt = __shfl_up(s, d); if (lane >= d) s += tt; }
    if (lane == 63) ws[w] = s;
    __syncthreads();
    int off = 0;
    for (int u = 0; u < w; ++u) off += ws[u];
    binStart[255 - t] = off + s - v;
  }
}

// finalize rowstart/cursor + place nodes into LPT perm (LDS cursors only)
__global__ __launch_bounds__(256) void scan_add_place(
    int* __restrict__ rs, const int* __restrict__ boffs, int* __restrict__ cursor,
    const int* __restrict__ counts, const int* __restrict__ binStart,
    const int* __restrict__ blockBase, int* __restrict__ perm, int n, int E) {
  __shared__ int lcur[256];
  lcur[threadIdx.x] = binStart[threadIdx.x] + blockBase[blockIdx.x * 256 + threadIdx.x];
  __syncthreads();
  int i = blockIdx.x * 256 + threadIdx.x;
  if (i < n) {
    int v = rs[i] + boffs[blockIdx.x];
    rs[i] = v;
    cursor[i] = v;
    int d = counts[i]; if (d > 255) d = 255;
    perm[atomicAdd(&lcur[d], 1)] = i;
  }
  if (i == 0) rs[n] = E;
}

__global__ __launch_bounds__(256) void scatter_kernel(const int* __restrict__ src, const int* __restrict__ dst,
                                                      int* __restrict__ cursor, int* __restrict__ csr, int E) {
  int e = blockIdx.x * 256 + threadIdx.x;
  if (e < E) {
    int p = atomicAdd(&cursor[dst[e]], 1);
    csr[p] = src[e];
  }
}

// ---------------- edge aggregation helpers ----------------
template<int VEC>
__device__ __forceinline__ void load_row(const unsigned short* __restrict__ base,
                                         int s, int lane, float* v) {
  if constexpr (VEC == 4) {
    u16x4v r = *reinterpret_cast<const u16x4v*>(base + (size_t)s * 256 + lane * 4);
    #pragma unroll
    for (int j = 0; j < 4; ++j) v[j] = bf2f(r[j]);
  } else {
    v[0] = bf2f(base[(size_t)s * 64 + lane]);
  }
}

template<int VEC, int GROUP>
__device__ __forceinline__ float edge_score(const float* xv, const float* xrv, const float* attv) {
  float p = 0.f;
  #pragma unroll
  for (int j = 0; j < VEC; ++j) {
    float tv = xv[j] + xrv[j];
    tv = fmaxf(tv, 0.2f * tv);     // leaky_relu slope 0.2
    p = fmaf(tv, attv[j], p);
  }
  p = row16_sum(p);                // DPP, VALU-latency
  if constexpr (GROUP == 64) {     // cross-row stages for H=1
    p += __shfl_xor(p, 16);
    p += __shfl_xor(p, 32);
  }
  return p;
}

// one wave per dst node, LPT order via perm; online softmax w/ deferred-max,
// 4-edge unroll for memory-level parallelism.
template<int H, bool SELF, bool RELU>
__global__ __launch_bounds__(256) void edge_agg(
    const unsigned short* __restrict__ xl, const unsigned short* __restrict__ xr,
    const float* __restrict__ att, const float* __restrict__ bias,
    const int* __restrict__ rowstart, const int* __restrict__ csr,
    const int* __restrict__ perm,
    unsigned short* __restrict__ out, int N) {
  constexpr int F = H * 64;
  constexpr int VEC = F / 64;
  constexpr int GROUP = 64 / H;
  int wave = threadIdx.x >> 6, lane = threadIdx.x & 63;
  int gid = blockIdx.x * 4 + wave;
  if (gid >= N) return;
  int node = perm[gid];

  float attv[VEC];
  #pragma unroll
  for (int j = 0; j < VEC; ++j) attv[j] = att[lane * VEC + j];

  float xrv[VEC];
  load_row<VEC>(xr, node, lane, xrv);

  int s0 = rowstart[node], s1 = rowstart[node + 1];
  int end = s1 + (SELF ? 1 : 0);

  float m = 0.f, l = 0.f;
  float acc[VEC];
  #pragma unroll
  for (int j = 0; j < VEC; ++j) acc[j] = 0.f;

  int i = s0;
  if (i < end) {           // first edge: m := its score, w == 1
    int s = (i < s1) ? csr[i] : node;
    float xv[VEC];
    load_row<VEC>(xl, s, lane, xv);
    m = edge_score<VEC, GROUP>(xv, xrv, attv);
    l = 1.f;
    #pragma unroll
    for (int j = 0; j < VEC; ++j) acc[j] = xv[j];
    ++i;
  }
  for (; i + 4 <= end; i += 4) {
    int s_[4];
    float x_[4][VEC], p_[4], w_[4];
    #pragma unroll
    for (int q = 0; q < 4; ++q) s_[q] = (i + q < s1) ? csr[i + q] : node;
    #pragma unroll
    for (int q = 0; q < 4; ++q) load_row<VEC>(xl, s_[q], lane, x_[q]);
    #pragma unroll
    for (int q = 0; q < 4; ++q) p_[q] = edge_score<VEC, GROUP>(x_[q], xrv, attv);
    float mx = fmaxf(fmaxf(p_[0], p_[1]), fmaxf(p_[2], p_[3]));
    if (__any(mx > m + 8.f)) {
      float mn = fmaxf(m, mx);
      float sc = __expf(m - mn);
      l *= sc;
      #pragma unroll
      for (int j = 0; j < VEC; ++j) acc[j] *= sc;
      m = mn;
    }
    #pragma unroll
    for (int q = 0; q < 4; ++q) w_[q] = __expf(p_[q] - m);
    l += (w_[0] + w_[1]) + (w_[2] + w_[3]);
    #pragma unroll
    for (int j = 0; j < VEC; ++j)
      acc[j] = fmaf(w_[0], x_[0][j],
               fmaf(w_[1], x_[1][j],
               fmaf(w_[2], x_[2][j],
               fmaf(w_[3], x_[3][j], acc[j]))));
  }
  for (; i + 2 <= end; i += 2) {
    int sA = (i < s1) ? csr[i] : node;
    int sB = (i + 1 < s1) ? csr[i + 1] : node;
    float xa[VEC], xb[VEC];
    load_row<VEC>(xl, sA, lane, xa);
    load_row<VEC>(xl, sB, lane, xb);
    float pA = edge_score<VEC, GROUP>(xa, xrv, attv);
    float pB = edge_score<VEC, GROUP>(xb, xrv, attv);
    float mx = fmaxf(pA, pB);
    if (__any(mx > m + 8.f)) {
      float mn = fmaxf(m, mx);
      float sc = __expf(m - mn);
      l *= sc;
      #pragma unroll
      for (int j = 0; j < VEC; ++j) acc[j] *= sc;
      m = mn;
    }
    float wA = __expf(pA - m), wB = __expf(pB - m);
    l += wA + wB;
    #pragma unroll
    for (int j = 0; j < VEC; ++j) acc[j] = fmaf(wA, xa[j], fmaf(wB, xb[j], acc[j]));
  }
  if (i < end) {
    int s = (i < s1) ? csr[i] : node;
    float xv[VEC];
    load_row<VEC>(xl, s, lane, xv);
    float p = edge_score<VEC, GROUP>(xv, xrv, attv);
    if (__any(p > m + 8.f)) {
      float mn = fmaxf(m, p);
      float sc = __expf(m - mn);
      l *= sc;
      #pragma unroll
      for (int j = 0; j < VEC; ++j) acc[j] *= sc;
      m = mn;
    }
    float w = __expf(p - m);
    l += w;
    #pragma unroll
    for (int j = 0; j < VEC; ++j) acc[j] = fmaf(w, xv[j], acc[j]);
  }

  float rec = 1.f / (l + 1e-16f);
  if constexpr (VEC == 4) {
    u16x4v w4;
    #pragma unroll
    for (int j = 0; j < 4; ++j) {
      float o = fmaf(acc[j], rec, bias[lane * 4 + j]);
      if (RELU) o = fmaxf(o, 0.f);
      w4[j] = f2bf(o);
    }
    *reinterpret_cast<u16x4v*>(out + (size_t)node * 256 + lane * 4) = w4;
  } else {
    float o = fmaf(acc[0], rec, bias[lane]);
    if (RELU) o = fmaxf(o, 0.f);
    out[(size_t)node * 64 + lane] = f2bf(o);
  }
}

// ---------------- fused mean-pool + MLP + softmax: one block per graph ----------------
__global__ __launch_bounds__(256) void pool_mlp(
    const unsigned short* __restrict__ h, const int* __restrict__ batch,
    const float* __restrict__ w1, const float* __restrict__ b1,
    const float* __restrict__ w2, const float* __restrict__ b2,
    const float* __restrict__ w3, const float* __restrict__ b3,
    float* __restrict__ out, int N) {
  int g = blockIdx.x;
  int lo = 0, hi = N;
  while (lo < hi) { int mid = (lo + hi) >> 1; if (batch[mid] < g) lo = mid + 1; else hi = mid; }
  int n0 = lo;
  hi = N;
  while (lo < hi) { int mid = (lo + hi) >> 1; if (batch[mid] < g + 1) lo = mid + 1; else hi = mid; }
  int n1 = lo;

  int t = threadIdx.x;
  int c2 = t & 31, r = t >> 5;
  float ax = 0.f, ay = 0.f;
  for (int n = n0 + r; n < n1; n += 8) {
    unsigned int u = *reinterpret_cast<const unsigned int*>(h + (size_t)n * 64 + c2 * 2);
    ax += bf2f((unsigned short)(u & 0xffffu));
    ay += bf2f((unsigned short)(u >> 16));
  }
  __shared__ float redx[8][32], redy[8][32];
  __shared__ float sh[64];
  redx[r][c2] = ax; redy[r][c2] = ay;
  __syncthreads();
  if (t < 64) {
    int lane = t;
    float s = 0.f;
    #pragma unroll
    for (int q = 0; q < 8; ++q) s += (lane & 1) ? redy[q][lane >> 1] : redx[q][lane >> 1];
    float cnt = fmaxf((float)(n1 - n0), 1.f);
    sh[lane] = s / cnt;
    float h1 = b1[lane];
    for (int k = 0; k < 64; ++k) h1 = fmaf(sh[k], w1[k * 64 + lane], h1);
    h1 = fmaxf(h1, 0.f);
    sh[lane] = h1;
    float h2 = b2[lane];
    for (int k = 0; k < 64; ++k) h2 = fmaf(sh[k], w2[k * 64 + lane], h2);
    h2 = fmaxf(h2, 0.f);
    sh[lane] = h2;
    float lg = -INFINITY;
    if (lane < 12) {
      lg = b3[lane];
      for (int k = 0; k < 64; ++k) lg = fmaf(sh[k], w3[k * 12 + lane], lg);
    }
    float mx = lg;
    #pragma unroll
    for (int msk = 1; msk < 64; msk <<= 1) mx = fmaxf(mx, __shfl_xor(mx, msk));
    float ex = (lane < 12) ? __expf(lg - mx) : 0.f;
    float sm = ex;
    #pragma unroll
    for (int msk = 1; msk < 64; msk <<= 1) sm += __shfl_xor(sm, msk);
    if (lane < 12) out[(size_t)g * 12 + lane] = ex / sm;
  }
}

// ---------------- host ----------------
extern "C" void kernel_launch(void* const* d_in, const int* in_sizes, int n_in,
                              void* d_out, int out_size, void* d_ws, size_t ws_size,
                              hipStream_t stream) {
  const float* x    = (const float*)d_in[0];
  const int* edge   = (const int*)d_in[1];
  const int* batch  = (const int*)d_in[2];
  const float* W1l  = (const float*)d_in[3];
  const float* W1r  = (const float*)d_in[4];
  const float* a1   = (const float*)d_in[5];
  const float* b1   = (const float*)d_in[6];
  const float* W2l  = (const float*)d_in[7];
  const float* W2r  = (const float*)d_in[8];
  const float* a2   = (const float*)d_in[9];
  const float* b2   = (const float*)d_in[10];
  const float* W3l  = (const float*)d_in[11];
  const float* W3r  = (const float*)d_in[12];
  const float* a3   = (const float*)d_in[13];
  const float* b3   = (const float*)d_in[14];
  const float* lw1  = (const float*)d_in[15];
  const float* lb1  = (const float*)d_in[16];
  const float* lw2  = (const float*)d_in[17];
  const float* lb2  = (const float*)d_in[18];
  const float* lw3  = (const float*)d_in[19];
  const float* lb3  = (const float*)d_in[20];

  const int E = in_sizes[1] / 2;
  const int N = in_sizes[2];
  const int F0 = in_sizes[0] / N;   // 128
  const int G = out_size / 12;      // 512
  const int* src = edge;
  const int* dst = edge + E;

  const int gx = (N + 127) / 128;
  const int Mpad = gx * 128;        // padded rows so GLL staging never reads OOB
  const int nb = (N + 255) / 256;

  // workspace carve (256B aligned)
  char* p = (char*)d_ws;
  auto alloc = [&](size_t bytes) { char* q = p; p += (bytes + 255) & ~(size_t)255; return q; };
  unsigned short* bufA = (unsigned short*)alloc((size_t)Mpad * 256 * 2);
  unsigned short* bufB = (unsigned short*)alloc((size_t)Mpad * 256 * 2);
  unsigned short* bufH = (unsigned short*)alloc((size_t)Mpad * 256 * 2);
  unsigned short* Wt1L = (unsigned short*)alloc(128 * 256 * 2);
  unsigned short* Wt1R = (unsigned short*)alloc(128 * 256 * 2);
  unsigned short* Wt2L = (unsigned short*)alloc(256 * 256 * 2);
  unsigned short* Wt2R = (unsigned short*)alloc(256 * 256 * 2);
  unsigned short* Wt3L = (unsigned short*)alloc(256 * 64 * 2);
  unsigned short* Wt3R = (unsigned short*)alloc(256 * 64 * 2);
  int* counts    = (int*)alloc((size_t)N * 4);      // contiguous with binTotal for one memset
  int* binTotal  = (int*)alloc(256 * 4);
  int* binStart  = (int*)alloc(256 * 4);
  int* blockBase = (int*)alloc((size_t)nb * 256 * 4);
  int* rowstart  = (int*)alloc((size_t)(N + 1) * 4);
  int* cursor    = (int*)alloc((size_t)N * 4);
  int* perm      = (int*)alloc((size_t)N * 4);
  int* bsums     = (int*)alloc(4096 * 4);
  int* boffs     = (int*)alloc(4096 * 4);
  int* csr       = (int*)alloc((size_t)E * 4);

  // ---- CSR by dst + LPT perm (folded) ----
  size_t countsPad = ((size_t)N * 4 + 255) & ~(size_t)255;
  hipMemsetAsync(counts, 0, countsPad + 256 * 4, stream);   // counts + binTotal
  hist_kernel<<<(E + 255) / 256, 256, 0, stream>>>(dst, counts, E);
  scan_block_deg<<<nb, 256, 0, stream>>>(counts, rowstart, bsums, binTotal, blockBase, N);
  scan2_offsets<<<1, 256, 0, stream>>>(bsums, boffs, binTotal, binStart, nb);
  scan_add_place<<<nb, 256, 0, stream>>>(rowstart, boffs, cursor, counts, binStart, blockBase, perm, N, E);
  scatter_kernel<<<(E + 255) / 256, 256, 0, stream>>>(src, dst, cursor, csr, E);

  // ---- all weight transposes in one launch ----
  {
    WPack wp;
    const float* ins[6] = {W1l, W1r, W2l, W2r, W3l, W3r};
    unsigned short* outs[6] = {Wt1L, Wt1R, Wt2L, Wt2R, Wt3L, Wt3R};
    int Ks[6] = {F0, F0, 256, 256, 256, 256};
    int Ns[6] = {256, 256, 256, 256, 64, 64};
    int acc0 = 0;
    for (int s = 0; s < 6; ++s) {
      wp.in[s] = ins[s]; wp.out[s] = outs[s]; wp.K[s] = Ks[s]; wp.Ncol[s] = Ns[s];
      wp.start[s] = acc0; acc0 += Ks[s] * Ns[s];
    }
    wp.start[6] = acc0;
    convert_all<<<(acc0 + 255) / 256, 256, 0, stream>>>(wp);
  }

  int ne = (N + 3) / 4;

  // ---- conv1: K=128, Ncol=256, no self loops, relu; A = x (f32, reg-staged) ----
  gemm_dual<128, 2, 2, true, false><<<dim3(gx, 2, 2), 256, 0, stream>>>(x, Wt1L, Wt1R, bufA, bufB, N, F0, 256);
  edge_agg<4, false, true><<<ne, 256, 0, stream>>>(bufA, bufB, a1, b1, rowstart, csr, perm, bufH, N);

  // ---- conv2: K=256, Ncol=256, self loops, relu; A = bufH (bf16, GLL) ----
  gemm_dual<128, 2, 2, false, true><<<dim3(gx, 2, 2), 256, 0, stream>>>(bufH, Wt2L, Wt2R, bufA, bufB, N, 256, 256);
  edge_agg<4, true, true><<<ne, 256, 0, stream>>>(bufA, bufB, a2, b2, rowstart, csr, perm, bufH, N);

  // ---- conv3: K=256, Ncol=64, self loops, no relu; A = bufH (bf16, GLL) ----
  gemm_dual<64, 4, 1, false, true><<<dim3(gx, 1, 2), 256, 0, stream>>>(bufH, Wt3L, Wt3R, bufA, bufB, N, 256, 64);
  edge_agg<1, true, false><<<ne, 256, 0, stream>>>(bufA, bufB, a3, b3, rowstart, csr, perm, bufH, N);

  // ---- fused mean pool + MLP head + softmax (one block per graph) ----
  pool_mlp<<<G, 256, 0, stream>>>(bufH, batch, lw1, lb1, lw2, lb2, lw3, lb3,
                                  (float*)d_out, N);
}